// Round 7
// baseline (423.659 us; speedup 1.0000x reference)
//
#include <hip/hip_runtime.h>
#include <math.h>
#include <stdint.h>

#define BB 2
#define NN 512
#define CC 256
#define HH 256
#define WW 256
#define DIN 12544    // C * 7 * 7
#define OUT1 1024
#define NCLS 11      // NUM_CLASSES + 1
#define NROI 1024    // B * N
#define SK1 8        // split-K for FC1 (Ks = 12544/8 = 1568, %32 == 0)
#define SK2 2        // split-K for FC2
#define NWB 1696     // weight-convert blocks: 1568 (W1) + 128 (W2)

typedef short bf16x8 __attribute__((ext_vector_type(8)));
typedef float f32x4 __attribute__((ext_vector_type(4)));
typedef unsigned short u16x8 __attribute__((ext_vector_type(8)));

__device__ inline unsigned short f2bf(float f) {
  unsigned int u = __float_as_uint(f);
  u += 0x7FFF + ((u >> 16) & 1);  // round-to-nearest-even
  return (unsigned short)(u >> 16);
}
__device__ inline float bf2f(unsigned short h) {
  return __uint_as_float(((unsigned int)h) << 16);
}

// async global->LDS, 16B per lane; lds ptr must be wave-uniform base + lane*16
__device__ inline void gll16(const void* g, void* l) {
  __builtin_amdgcn_global_load_lds(
      reinterpret_cast<const __attribute__((address_space(1))) void*>(
          reinterpret_cast<uintptr_t>(g)),
      reinterpret_cast<__attribute__((address_space(3))) void*>(
          (unsigned int)reinterpret_cast<uintptr_t>(l)),
      16, 0, 0);
}

// ---------------------------------------------------------------------------
// prep v4: NCHW fp32 -> NHWC bf16, LONG sequential reads.
// Block tile: 64c x 1024hw, as 8 subs of 8c x 1024hw (LDS 16.5 KB).
// Per sub: wave lanes 0-31 sweep one channel's 4KB in 8 back-to-back 512B
// wave-loads (lanes 32-63 the next channel) -> DRAM row-sequential reads.
// Every earlier variant read <=512B/channel scattered in time and all were
// pinned at ~2 TB/s (r5 proved writes/occupancy/conflicts don't matter).
// Writes: 16B/row fragments; each 128B L2 line is filled entirely by this
// block across its 8 subs (cgroup-adjacent blocks land on other XCDs).
// Grid: cgroup fastest (bid&3), hwt (bid>>2)&63, b = bid>>8. 512 blocks.
// ---------------------------------------------------------------------------
__global__ __launch_bounds__(256) void prep_feat(
    const float* __restrict__ feat, unsigned short* __restrict__ fhwc) {
  __shared__ unsigned short lds[8][1032];
  int bid = blockIdx.x;
  int tid = threadIdx.x;
  int cg = bid & 3;
  int hwt = (bid >> 2) & 63;
  int b = bid >> 8;
  int hw0 = hwt * 1024;
  int c0 = cg * 64;
  int ch = tid >> 5;   // 0..7 channel-in-sub
  int j = tid & 31;    // 512B sweep lane

  for (int sub = 0; sub < 8; ++sub) {
    const float* src =
        feat + ((size_t)b * CC + c0 + sub * 8 + ch) * (HH * WW) + hw0;
#pragma unroll
    for (int p = 0; p < 8; ++p) {
      float4 v = *(const float4*)(src + p * 128 + j * 4);
      ushort4 o;
      o.x = f2bf(v.x); o.y = f2bf(v.y); o.z = f2bf(v.z); o.w = f2bf(v.w);
      *(ushort4*)&lds[ch][p * 128 + j * 4] = o;
    }
    __syncthreads();
    unsigned short* dst = fhwc + ((size_t)b * (HH * WW) + hw0) * CC + c0 + sub * 8;
#pragma unroll
    for (int q = 0; q < 4; ++q) {
      int r = q * 256 + tid;
      ushort4 lo, hi;
      lo.x = lds[0][r]; lo.y = lds[1][r]; lo.z = lds[2][r]; lo.w = lds[3][r];
      hi.x = lds[4][r]; hi.y = lds[5][r]; hi.z = lds[6][r]; hi.w = lds[7][r];
      *(ushort4*)(dst + (size_t)r * CC) = lo;
      *(ushort4*)(dst + (size_t)r * CC + 4) = hi;
    }
    __syncthreads();
  }
}

// ---------------------------------------------------------------------------
__device__ inline void bilin(float gy, float gx, int& y0, int& x0, int& y1,
                             int& x1, float& w00, float& w01, float& w10,
                             float& w11) {
  float valid = (gy > -1.f && gy < 256.f && gx > -1.f && gx < 256.f) ? 0.25f : 0.f;
  float y = fminf(fmaxf(gy, 0.f), 255.f);
  float x = fminf(fmaxf(gx, 0.f), 255.f);
  float yf = floorf(y), xf = floorf(x);
  y0 = (int)yf; x0 = (int)xf;
  y1 = min(y0 + 1, 255); x1 = min(x0 + 1, 255);
  float ly = y - yf, lx = x - xf, hy = 1.f - ly, hx = 1.f - lx;
  w00 = hy * hx * valid; w01 = hy * lx * valid;
  w10 = ly * hx * valid; w11 = ly * lx * valid;
}

// ---------------------------------------------------------------------------
// Fused: ROI align (blocks [0, roi_cnt)) + weight conversion (blocks
// [roi_cnt, roi_cnt+NWB)). ROI first (overlap regimes, r4: -6us).
// roi: 16B/lane gathers, lane halves cover the two x-neighbors (r6).
// ---------------------------------------------------------------------------
__global__ __launch_bounds__(256) void roi_fused(
    const unsigned short* __restrict__ fhwc, const float* __restrict__ props,
    unsigned short* __restrict__ pooled, const float* __restrict__ W1,
    unsigned short* __restrict__ W1T, const float* __restrict__ W2,
    unsigned short* __restrict__ W2T, int roi_cnt) {
  __shared__ unsigned short tile[64 * 132];
  int bid = blockIdx.x;
  int tid = threadIdx.x;

  if (bid >= roi_cnt) {
    // ---- weight convert (perm gather) ----
    int u = bid - roi_cnt;
    const float* in;
    unsigned short* out;
    int Kout, kblk, nblk;
    bool perm;
    if (u < 1568) {
      in = W1; out = W1T; Kout = DIN; kblk = u % 196; nblk = u / 196;
      perm = true;
    } else {
      u -= 1568;
      in = W2; out = W2T; Kout = OUT1; kblk = u & 15; nblk = u >> 4;
      perm = false;
    }
    int k0 = kblk * 64, n0 = nblk * 128;
    int kl_base = tid >> 5;        // 0..7
    int nq = (tid & 31) * 4;       // 0..124
#pragma unroll
    for (int pass = 0; pass < 8; ++pass) {
      int kl = kl_base + pass * 8;
      int k = k0 + kl;
      int row = perm ? ((k & 255) * 49 + (k >> 8)) : k;
      float4 v = *(const float4*)(in + (size_t)row * OUT1 + n0 + nq);
      ushort4 o;
      o.x = f2bf(v.x); o.y = f2bf(v.y); o.z = f2bf(v.z); o.w = f2bf(v.w);
      *(ushort4*)&tile[kl * 132 + nq] = o;
    }
    __syncthreads();
    int hi = tid >> 4, lo = tid & 15;
#pragma unroll
    for (int pass = 0; pass < 8; ++pass) {
      int nl = hi + pass * 16;
      int kq = lo * 4;
      ushort4 o;
      o.x = tile[(kq + 0) * 132 + nl];
      o.y = tile[(kq + 1) * 132 + nl];
      o.z = tile[(kq + 2) * 132 + nl];
      o.w = tile[(kq + 3) * 132 + nl];
      *(ushort4*)(out + (size_t)(n0 + nl) * Kout + k0 + kq) = o;
    }
    return;
  }

  // ---- ROI align rotated from NHWC bf16 (16B/lane) ----
  int roi = bid >> 1;
  int half = bid & 1;
  int b = roi >> 9;
  const float* p = props + (size_t)roi * 5;
  float cx = p[0], cy = p[1], w = p[2], h = p[3], th = p[4];
  float sn = sinf(th), cs = cosf(th);
  int wave = tid >> 6, lane = tid & 63;
  int hi32 = lane >> 5;          // which x-neighbor of the pair
  int c8 = (lane & 31) * 8;      // 8 channels per lane
  const unsigned short* fb = fhwc + (size_t)b * HH * WW * CC;
  unsigned short* outp = pooled + (size_t)roi * DIN;

  for (int bin = half * 4 + wave; bin < 49; bin += 8) {
    int py = bin / 7, px = bin - py * 7;
    float acc[8] = {0.f, 0.f, 0.f, 0.f, 0.f, 0.f, 0.f, 0.f};
    const unsigned short* ptr[8];
    float wsel[8];
#pragma unroll
    for (int s = 0; s < 4; ++s) {
      int sy = s >> 1, sx = s & 1;
      float ys = -0.5f * h + (h / 7.0f) * ((float)py + ((float)sy + 0.5f) * 0.5f);
      float xs = -0.5f * w + (w / 7.0f) * ((float)px + ((float)sx + 0.5f) * 0.5f);
      float gx = cx + xs * cs - ys * sn;
      float gy = cy + xs * sn + ys * cs;
      int y0, x0, y1, x1; float w00, w01, w10, w11;
      bilin(gy, gx, y0, x0, y1, x1, w00, w01, w10, w11);
      int xa = hi32 ? x1 : x0;
      ptr[s * 2 + 0] = fb + ((size_t)(y0 * WW + xa)) * CC + c8;
      wsel[s * 2 + 0] = hi32 ? w01 : w00;
      ptr[s * 2 + 1] = fb + ((size_t)(y1 * WW + xa)) * CC + c8;
      wsel[s * 2 + 1] = hi32 ? w11 : w10;
    }
    u16x8 v[8];
#pragma unroll
    for (int t = 0; t < 8; ++t) v[t] = *(const u16x8*)ptr[t];
#pragma unroll
    for (int t = 0; t < 8; ++t) {
      float wt = wsel[t];
#pragma unroll
      for (int e = 0; e < 8; ++e) acc[e] += wt * bf2f(v[t][e]);
    }
#pragma unroll
    for (int e = 0; e < 8; ++e) acc[e] += __shfl_xor(acc[e], 32);
    if (lane < 32) {
      u16x8 o;
#pragma unroll
      for (int e = 0; e < 8; ++e) o[e] = f2bf(acc[e]);
      *(u16x8*)(outp + bin * 256 + c8) = o;
    }
  }
}

// Fallback: direct NCHW gather (small-ws path)
__global__ __launch_bounds__(256) void roi_align_nchw(
    const float* __restrict__ feat, const float* __restrict__ props,
    unsigned short* __restrict__ pooled) {
  int roi = blockIdx.x;
  int b = roi >> 9;
  int c = threadIdx.x;
  const float* p = props + (size_t)roi * 5;
  float cx = p[0], cy = p[1], w = p[2], h = p[3], th = p[4];
  float sn = sinf(th), cs = cosf(th);
  const float* fb = feat + ((size_t)b * CC + c) * (HH * WW);
  unsigned short* outp = pooled + (size_t)roi * DIN;
  for (int bin = 0; bin < 49; ++bin) {
    int py = bin / 7, px = bin - py * 7;
    float acc = 0.f;
#pragma unroll
    for (int sy = 0; sy < 2; ++sy) {
#pragma unroll
      for (int sx = 0; sx < 2; ++sx) {
        float ys = -0.5f * h + (h / 7.0f) * ((float)py + ((float)sy + 0.5f) * 0.5f);
        float xs = -0.5f * w + (w / 7.0f) * ((float)px + ((float)sx + 0.5f) * 0.5f);
        float gx = cx + xs * cs - ys * sn;
        float gy = cy + xs * sn + ys * cs;
        int y0, x0, y1, x1; float w00, w01, w10, w11;
        bilin(gy, gx, y0, x0, y1, x1, w00, w01, w10, w11);
        acc += w00 * fb[(size_t)y0 * WW + x0] + w01 * fb[(size_t)y0 * WW + x1] +
               w10 * fb[(size_t)y1 * WW + x0] + w11 * fb[(size_t)y1 * WW + x1];
      }
    }
    outp[bin * 256 + c] = f2bf(acc);
  }
}

// ---------------------------------------------------------------------------
// MFMA GEMM, 128x128 tile, BK=32, split-K partials (fp32, no bias).
// A [M][K] bf16 row-major; Bw [N][K] bf16 row-major. (m97 structure)
// ---------------------------------------------------------------------------
__global__ __launch_bounds__(256) void gemm_mfma_128(
    const unsigned short* __restrict__ A, const unsigned short* __restrict__ Bw,
    float* __restrict__ part, int K, int Ks) {
  __shared__ short As[128 * 32];
  __shared__ short Bs[128 * 32];
  int tid = threadIdx.x;
  int w = tid >> 6, lane = tid & 63;
  int quad = lane >> 4, l16 = lane & 15;
  int m0 = blockIdx.y * 128, n0 = blockIdx.x * 128;
  int bz = blockIdx.z;
  int wm = w >> 1, wn = w & 1;

  const char* pA = (const char*)A +
      ((size_t)(m0 + 32 * w + (lane >> 2)) * K + (size_t)bz * Ks) * 2 +
      (lane & 3) * 16;
  const char* pB = (const char*)Bw +
      ((size_t)(n0 + 32 * w + (lane >> 2)) * K + (size_t)bz * Ks) * 2 +
      (lane & 3) * 16;
  short* la = &As[w * 1024];
  short* lb = &Bs[w * 1024];
  const size_t rstep = (size_t)K * 2 * 16;  // +16 rows

  f32x4 acc[4][4] = {};
  int aoff[4], boff[4];
#pragma unroll
  for (int t = 0; t < 4; ++t) {
    aoff[t] = (wm * 64 + t * 16 + l16) * 32 + quad * 8;
    boff[t] = (wn * 64 + t * 16 + l16) * 32 + quad * 8;
  }

  for (int kk = 0; kk < Ks; kk += 32) {
    __syncthreads();  // prior reads done before LDS overwrite
    gll16(pA, la);
    gll16(pA + rstep, la + 512);
    gll16(pB, lb);
    gll16(pB + rstep, lb + 512);
    pA += 64; pB += 64;
    __syncthreads();  // vmcnt(0) drained -> LDS valid
    bf16x8 af[4], bfr[4];
#pragma unroll
    for (int t = 0; t < 4; ++t) af[t] = *(const bf16x8*)&As[aoff[t]];
#pragma unroll
    for (int t = 0; t < 4; ++t) bfr[t] = *(const bf16x8*)&Bs[boff[t]];
#pragma unroll
    for (int mt = 0; mt < 4; ++mt)
#pragma unroll
      for (int nt = 0; nt < 4; ++nt)
        acc[mt][nt] = __builtin_amdgcn_mfma_f32_16x16x32_bf16(
            af[mt], bfr[nt], acc[mt][nt], 0, 0, 0);
  }

  float* pp = part + (size_t)bz * (OUT1 * NROI);
#pragma unroll
  for (int mt = 0; mt < 4; ++mt)
#pragma unroll
    for (int nt = 0; nt < 4; ++nt) {
      int col = n0 + wn * 64 + nt * 16 + l16;
#pragma unroll
      for (int r = 0; r < 4; ++r) {
        int row = m0 + wm * 64 + mt * 16 + quad * 4 + r;
        pp[(size_t)row * OUT1 + col] = acc[mt][nt][r];
      }
    }
}

// split-K reduce + bias + relu -> bf16 (SK1 partials)
__global__ __launch_bounds__(256) void reduce_relu_bf16(
    const float* __restrict__ part, const float* __restrict__ bias,
    unsigned short* __restrict__ out) {
  int i = blockIdx.x * 256 + threadIdx.x;  // float4 index
  int base = i * 4;
  int col = base & (OUT1 - 1);
  const float4* p = (const float4*)part;
  float4 s = p[i];
#pragma unroll
  for (int z = 1; z < SK1; ++z) {
    float4 t = p[i + (size_t)z * (NROI * OUT1 / 4)];
    s.x += t.x; s.y += t.y; s.z += t.z; s.w += t.w;
  }
  float4 bv = *(const float4*)(bias + col);
  ushort4 o;
  o.x = f2bf(fmaxf(s.x + bv.x, 0.f));
  o.y = f2bf(fmaxf(s.y + bv.y, 0.f));
  o.z = f2bf(fmaxf(s.z + bv.z, 0.f));
  o.w = f2bf(fmaxf(s.w + bv.w, 0.f));
  *(ushort4*)(out + base) = o;
}

// ---------------------------------------------------------------------------
// MFMA GEMM, 64x64 tile, BK=64, split-K partials fp32. A[M][K], Bw[N][K].
// ---------------------------------------------------------------------------
__global__ __launch_bounds__(256) void gemm_mfma_64_part(
    const unsigned short* __restrict__ A, const unsigned short* __restrict__ Bw,
    float* __restrict__ part, int K, int Ks) {
  __shared__ short As[64 * 64];
  __shared__ short Bs[64 * 64];
  int tid = threadIdx.x;
  int w = tid >> 6, lane = tid & 63;
  int quad = lane >> 4, l16 = lane & 15;
  int m0 = blockIdx.y * 64, n0 = blockIdx.x * 64;
  int bz = blockIdx.z;
  int wm = w >> 1, wn = w & 1;

  const char* pA = (const char*)A +
      ((size_t)(m0 + 16 * w + (lane >> 3)) * K + (size_t)bz * Ks) * 2 +
      (lane & 7) * 16;
  const char* pB = (const char*)Bw +
      ((size_t)(n0 + 16 * w + (lane >> 3)) * K + (size_t)bz * Ks) * 2 +
      (lane & 7) * 16;
  short* la = &As[w * 1024];
  short* lb = &Bs[w * 1024];
  const size_t rstep = (size_t)K * 2 * 8;  // +8 rows

  f32x4 acc[2][2] = {};
  int aoff[2], boff[2];
#pragma unroll
  for (int t = 0; t < 2; ++t) {
    aoff[t] = (wm * 32 + t * 16 + l16) * 64 + quad * 8;
    boff[t] = (wn * 32 + t * 16 + l16) * 64 + quad * 8;
  }

  for (int kk = 0; kk < Ks; kk += 64) {
    __syncthreads();
    gll16(pA, la);
    gll16(pA + rstep, la + 512);
    gll16(pB, lb);
    gll16(pB + rstep, lb + 512);
    pA += 128; pB += 128;
    __syncthreads();
#pragma unroll
    for (int ks = 0; ks < 2; ++ks) {
      bf16x8 af[2], bfr[2];
#pragma unroll
      for (int t = 0; t < 2; ++t) af[t] = *(const bf16x8*)&As[aoff[t] + ks * 32];
#pragma unroll
      for (int t = 0; t < 2; ++t) bfr[t] = *(const bf16x8*)&Bs[boff[t] + ks * 32];
#pragma unroll
      for (int mt = 0; mt < 2; ++mt)
#pragma unroll
        for (int nt = 0; nt < 2; ++nt)
          acc[mt][nt] = __builtin_amdgcn_mfma_f32_16x16x32_bf16(
              af[mt], bfr[nt], acc[mt][nt], 0, 0, 0);
    }
  }
  float* pp = part + (size_t)bz * (OUT1 * NROI);
#pragma unroll
  for (int mt = 0; mt < 2; ++mt)
#pragma unroll
    for (int nt = 0; nt < 2; ++nt) {
      int col = n0 + wn * 32 + nt * 16 + l16;
#pragma unroll
      for (int r = 0; r < 4; ++r) {
        int row = m0 + wm * 32 + mt * 16 + quad * 4 + r;
        pp[(size_t)row * OUT1 + col] = acc[mt][nt][r];
      }
    }
}

// ---------------------------------------------------------------------------
// Head: x2 = relu(p0+p1+b2) on the fly; cls/reg GEMV + box decode.
// ---------------------------------------------------------------------------
__global__ __launch_bounds__(256) void head_kernel(
    const float* __restrict__ P0, const float* __restrict__ P1,
    const float* __restrict__ b2, const float* __restrict__ Wcls,
    const float* __restrict__ bcls, const float* __restrict__ Wreg,
    const float* __restrict__ breg, const float* __restrict__ props,
    float* __restrict__ out) {
  __shared__ float xrow[1024];
  __shared__ float partial[16][17];
  __shared__ float res[16];
  int row = blockIdx.x;
  int tid = threadIdx.x;
  {
    size_t off = (size_t)row * 1024 + tid * 4;
    float4 a = *(const float4*)(P0 + off);
    float4 b = *(const float4*)(P1 + off);
    float4 bv = *(const float4*)(b2 + tid * 4);
    xrow[tid * 4 + 0] = fmaxf(a.x + b.x + bv.x, 0.f);
    xrow[tid * 4 + 1] = fmaxf(a.y + b.y + bv.y, 0.f);
    xrow[tid * 4 + 2] = fmaxf(a.z + b.z + bv.z, 0.f);
    xrow[tid * 4 + 3] = fmaxf(a.w + b.w + bv.w, 0.f);
  }
  __syncthreads();
  int col = tid & 15, slice = tid >> 4;
  float s = 0.f;
  if (col < NCLS) {
    for (int k = slice * 64; k < slice * 64 + 64; ++k)
      s += xrow[k] * Wcls[(size_t)k * NCLS + col];
  } else {
    int rc = col - NCLS;
    for (int k = slice * 64; k < slice * 64 + 64; ++k)
      s += xrow[k] * Wreg[(size_t)k * 5 + rc];
  }
  partial[slice][col] = s;
  __syncthreads();
  if (tid < 16) {
    float t = 0.f;
    for (int sl = 0; sl < 16; ++sl) t += partial[sl][tid];
    t += (tid < NCLS) ? bcls[tid] : breg[tid - NCLS];
    res[tid] = t;
  }
  __syncthreads();
  if (tid < NCLS) out[5120 + (size_t)row * NCLS + tid] = res[tid];
  if (tid == 0) {
    const float* p = props + (size_t)row * 5;
    float p0 = p[0] * 4.f, p1 = p[1] * 4.f, p2 = p[2] * 4.f, p3 = p[3] * 4.f,
          p4 = p[4];
    float r0 = res[11], r1 = res[12], r2 = res[13], r3 = res[14], r4 = res[15];
    const float V = 4.135166556742356f;  // |log(16/1000)|
    float bx = p2 * r0 + p0;
    float by = p3 * r1 + p1;
    float bw = p2 * expf(fminf(fmaxf(r2, -V), V));
    float bh = p3 * expf(fminf(fmaxf(r3, -V), V));
    const float PI = 3.14159265358979323846f;
    float a = p4 + r4;
    float m = fmodf(a + PI * 0.5f, PI);
    if (m < 0.f) m += PI;
    float ba = m - PI * 0.5f;
    float* bo = out + (size_t)row * 5;
    bo[0] = bx; bo[1] = by; bo[2] = bw; bo[3] = bh; bo[4] = ba;
  }
}

// ---------------------------------------------------------------------------
extern "C" void kernel_launch(void* const* d_in, const int* in_sizes, int n_in,
                              void* d_out, int out_size, void* d_ws,
                              size_t ws_size, hipStream_t stream) {
  const float* feat  = (const float*)d_in[0];
  const float* props = (const float*)d_in[1];
  const float* W1    = (const float*)d_in[2];
  const float* b1    = (const float*)d_in[3];
  const float* W2    = (const float*)d_in[4];
  const float* b2    = (const float*)d_in[5];
  const float* Wcls  = (const float*)d_in[6];
  const float* bcls  = (const float*)d_in[7];
  const float* Wreg  = (const float*)d_in[8];
  const float* breg  = (const float*)d_in[9];
  float* out = (float*)d_out;

  char* wp = (char*)d_ws;
  unsigned short* pooled = (unsigned short*)wp; wp += (size_t)NROI * DIN * 2;
  unsigned short* W1T    = (unsigned short*)wp; wp += (size_t)OUT1 * DIN * 2;
  unsigned short* W2T    = (unsigned short*)wp; wp += (size_t)OUT1 * OUT1 * 2;
  unsigned short* x1     = (unsigned short*)wp; wp += (size_t)NROI * OUT1 * 2;
  float*          part1  = (float*)wp;          wp += (size_t)SK1 * NROI * OUT1 * 4;
  float*          part2  = (float*)wp;          wp += (size_t)SK2 * NROI * OUT1 * 4;
  unsigned short* fhwc   = (unsigned short*)wp;

  size_t need_min  = (size_t)(wp - (char*)d_ws);
  size_t need_full = need_min + (size_t)BB * CC * HH * WW * 2;

  if (ws_size >= need_full) {
    prep_feat<<<512, 256, 0, stream>>>(feat, fhwc);
    // roi blocks first, weight blocks last (overlap regimes)
    roi_fused<<<NROI * 2 + NWB, 256, 0, stream>>>(fhwc, props, pooled, W1, W1T,
                                                  W2, W2T, NROI * 2);
  } else {
    // weights still need conversion; roi gathers NCHW directly
    roi_fused<<<NWB, 256, 0, stream>>>(fhwc, props, pooled, W1, W1T, W2, W2T,
                                       0);
    roi_align_nchw<<<NROI, 256, 0, stream>>>(feat, props, pooled);
  }

  gemm_mfma_128<<<dim3(8, 8, SK1), 256, 0, stream>>>(pooled, W1T, part1, DIN,
                                                     DIN / SK1);
  reduce_relu_bf16<<<NROI * OUT1 / 1024, 256, 0, stream>>>(part1, b1, x1);
  gemm_mfma_64_part<<<dim3(16, 16, SK2), 256, 0, stream>>>(x1, W2T, part2, OUT1,
                                                           OUT1 / SK2);
  head_kernel<<<NROI, 256, 0, stream>>>(part2, part2 + (size_t)NROI * OUT1, b2,
                                        Wcls, bcls, Wreg, breg, props, out);
}

// Round 8
// 375.834 us; speedup vs baseline: 1.1272x; 1.1272x over previous
//
#include <hip/hip_runtime.h>
#include <math.h>
#include <stdint.h>

#define BB 2
#define NN 512
#define CC 256
#define HH 256
#define WW 256
#define DIN 12544    // C * 7 * 7
#define OUT1 1024
#define NCLS 11      // NUM_CLASSES + 1
#define NROI 1024    // B * N
#define SK1 8        // split-K for FC1 (Ks = 12544/8 = 1568, %32 == 0)
#define SK2 2        // split-K for FC2
#define NWB 1696     // weight-convert blocks: 1568 (W1) + 128 (W2)

typedef short bf16x8 __attribute__((ext_vector_type(8)));
typedef float f32x4 __attribute__((ext_vector_type(4)));
typedef unsigned short u16x8 __attribute__((ext_vector_type(8)));

__device__ inline unsigned short f2bf(float f) {
  unsigned int u = __float_as_uint(f);
  u += 0x7FFF + ((u >> 16) & 1);  // round-to-nearest-even
  return (unsigned short)(u >> 16);
}
__device__ inline float bf2f(unsigned short h) {
  return __uint_as_float(((unsigned int)h) << 16);
}

// async global->LDS, 16B per lane; lds ptr must be wave-uniform base + lane*16
__device__ inline void gll16(const void* g, void* l) {
  __builtin_amdgcn_global_load_lds(
      reinterpret_cast<const __attribute__((address_space(1))) void*>(
          reinterpret_cast<uintptr_t>(g)),
      reinterpret_cast<__attribute__((address_space(3))) void*>(
          (unsigned int)reinterpret_cast<uintptr_t>(l)),
      16, 0, 0);
}

// ---------------------------------------------------------------------------
// Feature transpose: NCHW fp32 -> NHWC bf16. Tile 128hw x 64c (r6 config —
// best measured; stays under the 76us fill floor). Transpose variants at
// other granularities/occupancies all measured 90-114us @ ~2 TB/s: this
// pattern is at its structural floor (~46% of d2d-copy ceiling).
// ---------------------------------------------------------------------------
__global__ __launch_bounds__(256) void prep_feat(
    const float* __restrict__ feat, unsigned short* __restrict__ fhwc) {
  __shared__ unsigned short tile[64 * 132];
  int bid = blockIdx.x;
  int tid = threadIdx.x;
  int hw0 = (bid & 511) * 128;
  int c0 = ((bid >> 9) & 3) * 64;
  int b = bid >> 11;
  int cl_base = tid >> 5;        // 0..7
  int hwq = (tid & 31) * 4;      // 0..124
#pragma unroll
  for (int pass = 0; pass < 8; ++pass) {
    int cl = cl_base + pass * 8;
    float4 v = *(const float4*)(feat + ((size_t)b * CC + c0 + cl) * (HH * WW) +
                                hw0 + hwq);
    ushort4 o;
    o.x = f2bf(v.x); o.y = f2bf(v.y); o.z = f2bf(v.z); o.w = f2bf(v.w);
    *(ushort4*)&tile[cl * 132 + hwq] = o;
  }
  __syncthreads();
  int hi = tid >> 4, lo = tid & 15;
#pragma unroll
  for (int pass = 0; pass < 8; ++pass) {
    int hwl = hi + pass * 16;
    int cq = lo * 4;
    ushort4 o;
    o.x = tile[(cq + 0) * 132 + hwl];
    o.y = tile[(cq + 1) * 132 + hwl];
    o.z = tile[(cq + 2) * 132 + hwl];
    o.w = tile[(cq + 3) * 132 + hwl];
    *(ushort4*)(fhwc + ((size_t)b * (HH * WW) + hw0 + hwl) * CC + c0 + cq) = o;
  }
}

// ---------------------------------------------------------------------------
__device__ inline void bilin(float gy, float gx, int& y0, int& x0, int& y1,
                             int& x1, float& w00, float& w01, float& w10,
                             float& w11) {
  float valid = (gy > -1.f && gy < 256.f && gx > -1.f && gx < 256.f) ? 0.25f : 0.f;
  float y = fminf(fmaxf(gy, 0.f), 255.f);
  float x = fminf(fmaxf(gx, 0.f), 255.f);
  float yf = floorf(y), xf = floorf(x);
  y0 = (int)yf; x0 = (int)xf;
  y1 = min(y0 + 1, 255); x1 = min(x0 + 1, 255);
  float ly = y - yf, lx = x - xf, hy = 1.f - ly, hx = 1.f - lx;
  w00 = hy * hx * valid; w01 = hy * lx * valid;
  w10 = ly * hx * valid; w11 = ly * lx * valid;
}

// ---------------------------------------------------------------------------
// Fused: ROI align (blocks [0, roi_cnt)) + weight conversion (blocks
// [roi_cnt, roi_cnt+NWB)). ROI first (overlap regimes, r4: -6us).
// roi v3: 16B/lane gathers (r6) + 2-BIN SOFTWARE PIPELINE — issue bin i+1's
// 8 scattered loads before consuming bin i, so one bin of L2/L3 latency
// (~200-500cy) hides under the accumulate/shfl/store of the previous bin.
// ---------------------------------------------------------------------------
__global__ __launch_bounds__(256) void roi_fused(
    const unsigned short* __restrict__ fhwc, const float* __restrict__ props,
    unsigned short* __restrict__ pooled, const float* __restrict__ W1,
    unsigned short* __restrict__ W1T, const float* __restrict__ W2,
    unsigned short* __restrict__ W2T, int roi_cnt) {
  __shared__ unsigned short tile[64 * 132];
  int bid = blockIdx.x;
  int tid = threadIdx.x;

  if (bid >= roi_cnt) {
    // ---- weight convert (perm gather) ----
    int u = bid - roi_cnt;
    const float* in;
    unsigned short* out;
    int Kout, kblk, nblk;
    bool perm;
    if (u < 1568) {
      in = W1; out = W1T; Kout = DIN; kblk = u % 196; nblk = u / 196;
      perm = true;
    } else {
      u -= 1568;
      in = W2; out = W2T; Kout = OUT1; kblk = u & 15; nblk = u >> 4;
      perm = false;
    }
    int k0 = kblk * 64, n0 = nblk * 128;
    int kl_base = tid >> 5;        // 0..7
    int nq = (tid & 31) * 4;       // 0..124
#pragma unroll
    for (int pass = 0; pass < 8; ++pass) {
      int kl = kl_base + pass * 8;
      int k = k0 + kl;
      int row = perm ? ((k & 255) * 49 + (k >> 8)) : k;
      float4 v = *(const float4*)(in + (size_t)row * OUT1 + n0 + nq);
      ushort4 o;
      o.x = f2bf(v.x); o.y = f2bf(v.y); o.z = f2bf(v.z); o.w = f2bf(v.w);
      *(ushort4*)&tile[kl * 132 + nq] = o;
    }
    __syncthreads();
    int hi = tid >> 4, lo = tid & 15;
#pragma unroll
    for (int pass = 0; pass < 8; ++pass) {
      int nl = hi + pass * 16;
      int kq = lo * 4;
      ushort4 o;
      o.x = tile[(kq + 0) * 132 + nl];
      o.y = tile[(kq + 1) * 132 + nl];
      o.z = tile[(kq + 2) * 132 + nl];
      o.w = tile[(kq + 3) * 132 + nl];
      *(ushort4*)(out + (size_t)(n0 + nl) * Kout + k0 + kq) = o;
    }
    return;
  }

  // ---- ROI align rotated from NHWC bf16 (16B/lane, 2-bin pipeline) ----
  int roi = bid >> 1;
  int half = bid & 1;
  int b = roi >> 9;
  const float* p = props + (size_t)roi * 5;
  float cx = p[0], cy = p[1], w = p[2], h = p[3], th = p[4];
  float sn = sinf(th), cs = cosf(th);
  int wave = tid >> 6, lane = tid & 63;
  int hi32 = lane >> 5;          // which x-neighbor of the pair
  int c8 = (lane & 31) * 8;      // 8 channels per lane
  const unsigned short* fb = fhwc + (size_t)b * HH * WW * CC;
  unsigned short* outp = pooled + (size_t)roi * DIN;

  auto mkaddr = [&](int bn, const unsigned short** pp, float* ww) {
    int py = bn / 7, px = bn - py * 7;
#pragma unroll
    for (int s = 0; s < 4; ++s) {
      int sy = s >> 1, sx = s & 1;
      float ys = -0.5f * h + (h / 7.0f) * ((float)py + ((float)sy + 0.5f) * 0.5f);
      float xs = -0.5f * w + (w / 7.0f) * ((float)px + ((float)sx + 0.5f) * 0.5f);
      float gx = cx + xs * cs - ys * sn;
      float gy = cy + xs * sn + ys * cs;
      int y0, x0, y1, x1; float w00, w01, w10, w11;
      bilin(gy, gx, y0, x0, y1, x1, w00, w01, w10, w11);
      int xa = hi32 ? x1 : x0;
      pp[s * 2 + 0] = fb + ((size_t)(y0 * WW + xa)) * CC + c8;
      ww[s * 2 + 0] = hi32 ? w01 : w00;
      pp[s * 2 + 1] = fb + ((size_t)(y1 * WW + xa)) * CC + c8;
      ww[s * 2 + 1] = hi32 ? w11 : w10;
    }
  };

  int bin = half * 4 + wave;     // start 0..7, stride 8 (wave-uniform)
  const unsigned short* ptr[8];
  float wsel[8];
  u16x8 v[8];
  mkaddr(bin, ptr, wsel);
#pragma unroll
  for (int t = 0; t < 8; ++t) v[t] = *(const u16x8*)ptr[t];

  while (bin < 49) {
    int nbin = bin + 8;
    bool more = nbin < 49;       // wave-uniform
    const unsigned short* nptr[8];
    float nwsel[8];
    u16x8 nv[8];
    if (more) {
      mkaddr(nbin, nptr, nwsel);
#pragma unroll
      for (int t = 0; t < 8; ++t) nv[t] = *(const u16x8*)nptr[t];
    }
    float acc[8] = {0.f, 0.f, 0.f, 0.f, 0.f, 0.f, 0.f, 0.f};
#pragma unroll
    for (int t = 0; t < 8; ++t) {
      float wt = wsel[t];
#pragma unroll
      for (int e = 0; e < 8; ++e) acc[e] += wt * bf2f(v[t][e]);
    }
#pragma unroll
    for (int e = 0; e < 8; ++e) acc[e] += __shfl_xor(acc[e], 32);
    if (lane < 32) {
      u16x8 o;
#pragma unroll
      for (int e = 0; e < 8; ++e) o[e] = f2bf(acc[e]);
      *(u16x8*)(outp + bin * 256 + c8) = o;
    }
    bin = nbin;
    if (more) {
#pragma unroll
      for (int t = 0; t < 8; ++t) { v[t] = nv[t]; wsel[t] = nwsel[t]; }
    }
  }
}

// Fallback: direct NCHW gather (small-ws path)
__global__ __launch_bounds__(256) void roi_align_nchw(
    const float* __restrict__ feat, const float* __restrict__ props,
    unsigned short* __restrict__ pooled) {
  int roi = blockIdx.x;
  int b = roi >> 9;
  int c = threadIdx.x;
  const float* p = props + (size_t)roi * 5;
  float cx = p[0], cy = p[1], w = p[2], h = p[3], th = p[4];
  float sn = sinf(th), cs = cosf(th);
  const float* fb = feat + ((size_t)b * CC + c) * (HH * WW);
  unsigned short* outp = pooled + (size_t)roi * DIN;
  for (int bin = 0; bin < 49; ++bin) {
    int py = bin / 7, px = bin - py * 7;
    float acc = 0.f;
#pragma unroll
    for (int sy = 0; sy < 2; ++sy) {
#pragma unroll
      for (int sx = 0; sx < 2; ++sx) {
        float ys = -0.5f * h + (h / 7.0f) * ((float)py + ((float)sy + 0.5f) * 0.5f);
        float xs = -0.5f * w + (w / 7.0f) * ((float)px + ((float)sx + 0.5f) * 0.5f);
        float gx = cx + xs * cs - ys * sn;
        float gy = cy + xs * sn + ys * cs;
        int y0, x0, y1, x1; float w00, w01, w10, w11;
        bilin(gy, gx, y0, x0, y1, x1, w00, w01, w10, w11);
        acc += w00 * fb[(size_t)y0 * WW + x0] + w01 * fb[(size_t)y0 * WW + x1] +
               w10 * fb[(size_t)y1 * WW + x0] + w11 * fb[(size_t)y1 * WW + x1];
      }
    }
    outp[bin * 256 + c] = f2bf(acc);
  }
}

// ---------------------------------------------------------------------------
// MFMA GEMM, 128x128 tile, BK=32, split-K partials (fp32, no bias).
// A [M][K] bf16 row-major; Bw [N][K] bf16 row-major. (m97 structure)
// ---------------------------------------------------------------------------
__global__ __launch_bounds__(256) void gemm_mfma_128(
    const unsigned short* __restrict__ A, const unsigned short* __restrict__ Bw,
    float* __restrict__ part, int K, int Ks) {
  __shared__ short As[128 * 32];
  __shared__ short Bs[128 * 32];
  int tid = threadIdx.x;
  int w = tid >> 6, lane = tid & 63;
  int quad = lane >> 4, l16 = lane & 15;
  int m0 = blockIdx.y * 128, n0 = blockIdx.x * 128;
  int bz = blockIdx.z;
  int wm = w >> 1, wn = w & 1;

  const char* pA = (const char*)A +
      ((size_t)(m0 + 32 * w + (lane >> 2)) * K + (size_t)bz * Ks) * 2 +
      (lane & 3) * 16;
  const char* pB = (const char*)Bw +
      ((size_t)(n0 + 32 * w + (lane >> 2)) * K + (size_t)bz * Ks) * 2 +
      (lane & 3) * 16;
  short* la = &As[w * 1024];
  short* lb = &Bs[w * 1024];
  const size_t rstep = (size_t)K * 2 * 16;  // +16 rows

  f32x4 acc[4][4] = {};
  int aoff[4], boff[4];
#pragma unroll
  for (int t = 0; t < 4; ++t) {
    aoff[t] = (wm * 64 + t * 16 + l16) * 32 + quad * 8;
    boff[t] = (wn * 64 + t * 16 + l16) * 32 + quad * 8;
  }

  for (int kk = 0; kk < Ks; kk += 32) {
    __syncthreads();  // prior reads done before LDS overwrite
    gll16(pA, la);
    gll16(pA + rstep, la + 512);
    gll16(pB, lb);
    gll16(pB + rstep, lb + 512);
    pA += 64; pB += 64;
    __syncthreads();  // vmcnt(0) drained -> LDS valid
    bf16x8 af[4], bfr[4];
#pragma unroll
    for (int t = 0; t < 4; ++t) af[t] = *(const bf16x8*)&As[aoff[t]];
#pragma unroll
    for (int t = 0; t < 4; ++t) bfr[t] = *(const bf16x8*)&Bs[boff[t]];
#pragma unroll
    for (int mt = 0; mt < 4; ++mt)
#pragma unroll
      for (int nt = 0; nt < 4; ++nt)
        acc[mt][nt] = __builtin_amdgcn_mfma_f32_16x16x32_bf16(
            af[mt], bfr[nt], acc[mt][nt], 0, 0, 0);
  }

  float* pp = part + (size_t)bz * (OUT1 * NROI);
#pragma unroll
  for (int mt = 0; mt < 4; ++mt)
#pragma unroll
    for (int nt = 0; nt < 4; ++nt) {
      int col = n0 + wn * 64 + nt * 16 + l16;
#pragma unroll
      for (int r = 0; r < 4; ++r) {
        int row = m0 + wm * 64 + mt * 16 + quad * 4 + r;
        pp[(size_t)row * OUT1 + col] = acc[mt][nt][r];
      }
    }
}

// split-K reduce + bias + relu -> bf16 (SK1 partials)
__global__ __launch_bounds__(256) void reduce_relu_bf16(
    const float* __restrict__ part, const float* __restrict__ bias,
    unsigned short* __restrict__ out) {
  int i = blockIdx.x * 256 + threadIdx.x;  // float4 index
  int base = i * 4;
  int col = base & (OUT1 - 1);
  const float4* p = (const float4*)part;
  float4 s = p[i];
#pragma unroll
  for (int z = 1; z < SK1; ++z) {
    float4 t = p[i + (size_t)z * (NROI * OUT1 / 4)];
    s.x += t.x; s.y += t.y; s.z += t.z; s.w += t.w;
  }
  float4 bv = *(const float4*)(bias + col);
  ushort4 o;
  o.x = f2bf(fmaxf(s.x + bv.x, 0.f));
  o.y = f2bf(fmaxf(s.y + bv.y, 0.f));
  o.z = f2bf(fmaxf(s.z + bv.z, 0.f));
  o.w = f2bf(fmaxf(s.w + bv.w, 0.f));
  *(ushort4*)(out + base) = o;
}

// ---------------------------------------------------------------------------
// MFMA GEMM, 64x64 tile, BK=64, split-K partials fp32. A[M][K], Bw[N][K].
// ---------------------------------------------------------------------------
__global__ __launch_bounds__(256) void gemm_mfma_64_part(
    const unsigned short* __restrict__ A, const unsigned short* __restrict__ Bw,
    float* __restrict__ part, int K, int Ks) {
  __shared__ short As[64 * 64];
  __shared__ short Bs[64 * 64];
  int tid = threadIdx.x;
  int w = tid >> 6, lane = tid & 63;
  int quad = lane >> 4, l16 = lane & 15;
  int m0 = blockIdx.y * 64, n0 = blockIdx.x * 64;
  int bz = blockIdx.z;
  int wm = w >> 1, wn = w & 1;

  const char* pA = (const char*)A +
      ((size_t)(m0 + 16 * w + (lane >> 3)) * K + (size_t)bz * Ks) * 2 +
      (lane & 7) * 16;
  const char* pB = (const char*)Bw +
      ((size_t)(n0 + 16 * w + (lane >> 3)) * K + (size_t)bz * Ks) * 2 +
      (lane & 7) * 16;
  short* la = &As[w * 1024];
  short* lb = &Bs[w * 1024];
  const size_t rstep = (size_t)K * 2 * 8;  // +8 rows

  f32x4 acc[2][2] = {};
  int aoff[2], boff[2];
#pragma unroll
  for (int t = 0; t < 2; ++t) {
    aoff[t] = (wm * 32 + t * 16 + l16) * 64 + quad * 8;
    boff[t] = (wn * 32 + t * 16 + l16) * 64 + quad * 8;
  }

  for (int kk = 0; kk < Ks; kk += 64) {
    __syncthreads();
    gll16(pA, la);
    gll16(pA + rstep, la + 512);
    gll16(pB, lb);
    gll16(pB + rstep, lb + 512);
    pA += 128; pB += 128;
    __syncthreads();
#pragma unroll
    for (int ks = 0; ks < 2; ++ks) {
      bf16x8 af[2], bfr[2];
#pragma unroll
      for (int t = 0; t < 2; ++t) af[t] = *(const bf16x8*)&As[aoff[t] + ks * 32];
#pragma unroll
      for (int t = 0; t < 2; ++t) bfr[t] = *(const bf16x8*)&Bs[boff[t] + ks * 32];
#pragma unroll
      for (int mt = 0; mt < 2; ++mt)
#pragma unroll
        for (int nt = 0; nt < 2; ++nt)
          acc[mt][nt] = __builtin_amdgcn_mfma_f32_16x16x32_bf16(
              af[mt], bfr[nt], acc[mt][nt], 0, 0, 0);
    }
  }
  float* pp = part + (size_t)bz * (OUT1 * NROI);
#pragma unroll
  for (int mt = 0; mt < 2; ++mt)
#pragma unroll
    for (int nt = 0; nt < 2; ++nt) {
      int col = n0 + wn * 32 + nt * 16 + l16;
#pragma unroll
      for (int r = 0; r < 4; ++r) {
        int row = m0 + wm * 32 + mt * 16 + quad * 4 + r;
        pp[(size_t)row * OUT1 + col] = acc[mt][nt][r];
      }
    }
}

// ---------------------------------------------------------------------------
// Head: x2 = relu(p0+p1+b2) on the fly; cls/reg GEMV + box decode.
// ---------------------------------------------------------------------------
__global__ __launch_bounds__(256) void head_kernel(
    const float* __restrict__ P0, const float* __restrict__ P1,
    const float* __restrict__ b2, const float* __restrict__ Wcls,
    const float* __restrict__ bcls, const float* __restrict__ Wreg,
    const float* __restrict__ breg, const float* __restrict__ props,
    float* __restrict__ out) {
  __shared__ float xrow[1024];
  __shared__ float partial[16][17];
  __shared__ float res[16];
  int row = blockIdx.x;
  int tid = threadIdx.x;
  {
    size_t off = (size_t)row * 1024 + tid * 4;
    float4 a = *(const float4*)(P0 + off);
    float4 b = *(const float4*)(P1 + off);
    float4 bv = *(const float4*)(b2 + tid * 4);
    xrow[tid * 4 + 0] = fmaxf(a.x + b.x + bv.x, 0.f);
    xrow[tid * 4 + 1] = fmaxf(a.y + b.y + bv.y, 0.f);
    xrow[tid * 4 + 2] = fmaxf(a.z + b.z + bv.z, 0.f);
    xrow[tid * 4 + 3] = fmaxf(a.w + b.w + bv.w, 0.f);
  }
  __syncthreads();
  int col = tid & 15, slice = tid >> 4;
  float s = 0.f;
  if (col < NCLS) {
    for (int k = slice * 64; k < slice * 64 + 64; ++k)
      s += xrow[k] * Wcls[(size_t)k * NCLS + col];
  } else {
    int rc = col - NCLS;
    for (int k = slice * 64; k < slice * 64 + 64; ++k)
      s += xrow[k] * Wreg[(size_t)k * 5 + rc];
  }
  partial[slice][col] = s;
  __syncthreads();
  if (tid < 16) {
    float t = 0.f;
    for (int sl = 0; sl < 16; ++sl) t += partial[sl][tid];
    t += (tid < NCLS) ? bcls[tid] : breg[tid - NCLS];
    res[tid] = t;
  }
  __syncthreads();
  if (tid < NCLS) out[5120 + (size_t)row * NCLS + tid] = res[tid];
  if (tid == 0) {
    const float* p = props + (size_t)row * 5;
    float p0 = p[0] * 4.f, p1 = p[1] * 4.f, p2 = p[2] * 4.f, p3 = p[3] * 4.f,
          p4 = p[4];
    float r0 = res[11], r1 = res[12], r2 = res[13], r3 = res[14], r4 = res[15];
    const float V = 4.135166556742356f;  // |log(16/1000)|
    float bx = p2 * r0 + p0;
    float by = p3 * r1 + p1;
    float bw = p2 * expf(fminf(fmaxf(r2, -V), V));
    float bh = p3 * expf(fminf(fmaxf(r3, -V), V));
    const float PI = 3.14159265358979323846f;
    float a = p4 + r4;
    float m = fmodf(a + PI * 0.5f, PI);
    if (m < 0.f) m += PI;
    float ba = m - PI * 0.5f;
    float* bo = out + (size_t)row * 5;
    bo[0] = bx; bo[1] = by; bo[2] = bw; bo[3] = bh; bo[4] = ba;
  }
}

// ---------------------------------------------------------------------------
extern "C" void kernel_launch(void* const* d_in, const int* in_sizes, int n_in,
                              void* d_out, int out_size, void* d_ws,
                              size_t ws_size, hipStream_t stream) {
  const float* feat  = (const float*)d_in[0];
  const float* props = (const float*)d_in[1];
  const float* W1    = (const float*)d_in[2];
  const float* b1    = (const float*)d_in[3];
  const float* W2    = (const float*)d_in[4];
  const float* b2    = (const float*)d_in[5];
  const float* Wcls  = (const float*)d_in[6];
  const float* bcls  = (const float*)d_in[7];
  const float* Wreg  = (const float*)d_in[8];
  const float* breg  = (const float*)d_in[9];
  float* out = (float*)d_out;

  char* wp = (char*)d_ws;
  unsigned short* pooled = (unsigned short*)wp; wp += (size_t)NROI * DIN * 2;
  unsigned short* W1T    = (unsigned short*)wp; wp += (size_t)OUT1 * DIN * 2;
  unsigned short* W2T    = (unsigned short*)wp; wp += (size_t)OUT1 * OUT1 * 2;
  unsigned short* x1     = (unsigned short*)wp; wp += (size_t)NROI * OUT1 * 2;
  float*          part1  = (float*)wp;          wp += (size_t)SK1 * NROI * OUT1 * 4;
  float*          part2  = (float*)wp;          wp += (size_t)SK2 * NROI * OUT1 * 4;
  unsigned short* fhwc   = (unsigned short*)wp;

  size_t need_min  = (size_t)(wp - (char*)d_ws);
  size_t need_full = need_min + (size_t)BB * CC * HH * WW * 2;

  if (ws_size >= need_full) {
    prep_feat<<<BB * 4 * (HH * WW / 128), 256, 0, stream>>>(feat, fhwc);
    // roi blocks first, weight blocks last (overlap regimes)
    roi_fused<<<NROI * 2 + NWB, 256, 0, stream>>>(fhwc, props, pooled, W1, W1T,
                                                  W2, W2T, NROI * 2);
  } else {
    // weights still need conversion; roi gathers NCHW directly
    roi_fused<<<NWB, 256, 0, stream>>>(fhwc, props, pooled, W1, W1T, W2, W2T,
                                       0);
    roi_align_nchw<<<NROI, 256, 0, stream>>>(feat, props, pooled);
  }

  gemm_mfma_128<<<dim3(8, 8, SK1), 256, 0, stream>>>(pooled, W1T, part1, DIN,
                                                     DIN / SK1);
  reduce_relu_bf16<<<NROI * OUT1 / 1024, 256, 0, stream>>>(part1, b1, x1);
  gemm_mfma_64_part<<<dim3(16, 16, SK2), 256, 0, stream>>>(x1, W2T, part2, OUT1,
                                                           OUT1 / SK2);
  head_kernel<<<NROI, 256, 0, stream>>>(part2, part2 + (size_t)NROI * OUT1, b2,
                                        Wcls, bcls, Wreg, breg, props, out);
}